// Round 10
// baseline (374.949 us; speedup 1.0000x reference)
//
#include <hip/hip_runtime.h>
#include <math.h>

#define NEG_SLOPE 0.2f

using f16   = _Float16;
using f16x4 = __attribute__((ext_vector_type(4))) _Float16;
using f16x8 = __attribute__((ext_vector_type(8))) _Float16;
using f32x4 = __attribute__((ext_vector_type(4))) float;

// ---------------- CSR build ----------------

__global__ void count_dst(const int* __restrict__ dst, int* __restrict__ counts, int E) {
    int e = blockIdx.x * blockDim.x + threadIdx.x;
    if (e < E) atomicAdd(&counts[dst[e]], 1);
}

// single-block exclusive scan over counts[n] (n <= 1024*49), writes indptr
// AND cursor (replaces scan_local+scan_carry+scan_add+memcpy: 3 launches + copy).
// Two passes over counts (L2-resident, 200 KB) to keep registers low.
__global__ __launch_bounds__(1024) void scan_all(const int* __restrict__ counts,
                                                 int* __restrict__ indptr,
                                                 int* __restrict__ cursor,
                                                 int n, int E) {
    __shared__ int ssum[1024];
    int t = threadIdx.x;
    int per = (n + 1023) >> 10;
    int base = t * per;
    int sum = 0;
    for (int j = 0; j < per; j++) {
        int idx = base + j;
        if (idx < n) sum += counts[idx];
    }
    ssum[t] = sum;
    __syncthreads();
    for (int o = 1; o < 1024; o <<= 1) {
        int u = (t >= o) ? ssum[t - o] : 0;
        __syncthreads();
        ssum[t] += u;
        __syncthreads();
    }
    int run = (t > 0) ? ssum[t - 1] : 0;
    for (int j = 0; j < per; j++) {
        int idx = base + j;
        if (idx < n) {
            indptr[idx] = run;
            cursor[idx] = run;
            run += counts[idx];
        }
    }
    if (t == 0) indptr[n] = E;
}

__global__ void fill_csr(const int* __restrict__ dst, const int* __restrict__ src,
                         int* __restrict__ cursor, int* __restrict__ csrc, int E) {
    int e = blockIdx.x * blockDim.x + threadIdx.x;
    if (e < E) {
        int p = atomicAdd(&cursor[dst[e]], 1);
        csrc[p] = src[e];
    }
}

// ---------------- edge el gather: elg[pos][h] = el[csrc[pos]][h] ----------------
// Dedicated kernel: the dependent random gather runs with full TLP (no
// barriers), so its latency is hidden by parallelism. agg then loads elg
// coalesced + independent (the R6/R9-fast property).

template <int HEADS>
__global__ __launch_bounds__(256) void elg_kernel(const float* __restrict__ el,
                                                  const int* __restrict__ csrc,
                                                  float* __restrict__ elg, int E) {
    int i = blockIdx.x * blockDim.x + threadIdx.x;
    if (i < E) {
        int sd = csrc[i];
        if constexpr (HEADS == 4)
            *(float4*)&elg[(size_t)i * 4] = *(const float4*)&el[(size_t)sd * 4];
        else
            elg[i] = el[sd];
    }
}

// ---------------- f16-MFMA GEMM + fused el/er ----------------
// C[M][BN] = A[M][256] * B[BN][256]^T (f16 out). Wave wn owns cols
// [64wn,64wn+64) = head wn, so el[row][wn] = sum(acc*al[col]) via 16-lane
// shfl reduce in the epilogue (saves a separate pass over h).

template <int BN, typename TA>
__global__ __launch_bounds__(256) void gemm_mfma(const TA* __restrict__ A,
                                                 const float* __restrict__ B,
                                                 f16* __restrict__ C,
                                                 const float* __restrict__ al,
                                                 const float* __restrict__ ar,
                                                 float* __restrict__ el,
                                                 float* __restrict__ er, int M) {
    constexpr int K = 256;
    constexpr int WAVES_N = BN / 64;
    constexpr int WAVES_M = 4 / WAVES_N;
    constexpr int WM = 64 / WAVES_M;
    constexpr int MF = WM / 16;

    __shared__ f16 as[64][40];
    __shared__ f16 bs[BN][40];

    int t = threadIdx.x;
    int wave = t >> 6, lane = t & 63;
    int wn = wave / WAVES_M;
    int wm = wave % WAVES_M;
    int row0 = blockIdx.x * 64;

    int srow = t >> 2;
    int skq = (t & 3) * 8;

    int lrow = lane & 15;
    int ksel = (lane >> 4) * 8;

    f32x4 acc[MF][4] = {};

    for (int k0 = 0; k0 < K; k0 += 32) {
        {
            int gr = row0 + srow;
            gr = gr < M ? gr : M - 1;
            if constexpr (sizeof(TA) == 4) {
                const float4* pa = (const float4*)(A + (size_t)gr * K + k0 + skq);
                float4 u0 = pa[0], u1 = pa[1];
                f16x8 av;
                av[0] = (f16)u0.x; av[1] = (f16)u0.y; av[2] = (f16)u0.z; av[3] = (f16)u0.w;
                av[4] = (f16)u1.x; av[5] = (f16)u1.y; av[6] = (f16)u1.z; av[7] = (f16)u1.w;
                *(f16x8*)&as[srow][skq] = av;
            } else {
                *(f16x8*)&as[srow][skq] = *(const f16x8*)(A + (size_t)gr * K + k0 + skq);
            }
        }
#pragma unroll
        for (int i = 0; i < BN / 64; i++) {
            int n = i * 64 + srow;
            const float4* pb = (const float4*)(B + (size_t)n * K + k0 + skq);
            float4 u0 = pb[0], u1 = pb[1];
            f16x8 bv;
            bv[0] = (f16)u0.x; bv[1] = (f16)u0.y; bv[2] = (f16)u0.z; bv[3] = (f16)u0.w;
            bv[4] = (f16)u1.x; bv[5] = (f16)u1.y; bv[6] = (f16)u1.z; bv[7] = (f16)u1.w;
            *(f16x8*)&bs[n][skq] = bv;
        }
        __syncthreads();

        f16x8 af[MF], bf[4];
#pragma unroll
        for (int i = 0; i < MF; i++)
            af[i] = *(const f16x8*)&as[wm * WM + i * 16 + lrow][ksel];
#pragma unroll
        for (int j = 0; j < 4; j++)
            bf[j] = *(const f16x8*)&bs[wn * 64 + j * 16 + lrow][ksel];
#pragma unroll
        for (int i = 0; i < MF; i++)
#pragma unroll
            for (int j = 0; j < 4; j++)
                acc[i][j] = __builtin_amdgcn_mfma_f32_16x16x32_f16(af[i], bf[j], acc[i][j], 0, 0, 0);
        __syncthreads();
    }

    // C store
#pragma unroll
    for (int i = 0; i < MF; i++) {
        int r0 = row0 + wm * WM + i * 16 + (lane >> 4) * 4;
#pragma unroll
        for (int j = 0; j < 4; j++) {
            int col = wn * 64 + j * 16 + (lane & 15);
#pragma unroll
            for (int r = 0; r < 4; r++) {
                int gr = r0 + r;
                if (gr < M) C[(size_t)gr * BN + col] = (f16)acc[i][j][r];
            }
        }
    }

    // fused el/er (head = wn)
#pragma unroll
    for (int i = 0; i < MF; i++) {
        float ea[4] = {}, eb[4] = {};
#pragma unroll
        for (int j = 0; j < 4; j++) {
            int col = wn * 64 + j * 16 + (lane & 15);
            float av = al[col], rv = ar[col];
#pragma unroll
            for (int r = 0; r < 4; r++) {
                ea[r] += acc[i][j][r] * av;
                eb[r] += acc[i][j][r] * rv;
            }
        }
#pragma unroll
        for (int o = 1; o <= 8; o <<= 1) {
#pragma unroll
            for (int r = 0; r < 4; r++) {
                ea[r] += __shfl_xor(ea[r], o);
                eb[r] += __shfl_xor(eb[r], o);
            }
        }
        if ((lane & 15) == 0) {
            int r0 = row0 + wm * WM + i * 16 + (lane >> 4) * 4;
#pragma unroll
            for (int r = 0; r < 4; r++) {
                int gr = r0 + r;
                if (gr < M) {
                    el[gr * WAVES_N + wn] = ea[r];
                    er[gr * WAVES_N + wn] = eb[r];
                }
            }
        }
    }
}

// ---------------- fused MFMA segment aggregation ----------------
// Block = 16 consecutive dst nodes. Per 32-edge K-step:
//  C[16n][D] += A[16n][32e] x H[32e][D], A[n][e] = w_e (owner-masked),
//  w_e = exp(leaky(elg[pos][h]+er[dst][h]) - CSH)  [unnormalized].
// Denominator via extra MFMA with B = ones column 0; divide in epilogue.
// issue(): rg gathers + elg load -- ALL independent loads (R9 property).
// 2-deep prefetch: named rgA/rgB + pkA/pkB; a buffer refilled in dostep(k)
// is consumed at dostep(k+64) -> ~2 steps (~500cy) of latency cover.
// dostep barrier section: pure LDS writes.
// Staging map: lane l, wave w, iter i -> LDS elem (i+NITER*w)*512 + 8l
// (linear per instruction: 0 write conflicts); layout matches tr_read.
// K-perm sigma(kb,j): j<4 -> 4*kb+j ; j>=4 -> 16+4*kb+(j-4); A uses same sigma.

template <int HEADS, bool RELU, typename TOUT>
__global__ __launch_bounds__(256) void agg_mfma(
        const f16* __restrict__ h, const float* __restrict__ elg,
        const float* __restrict__ er, const float* __restrict__ bias,
        const int* __restrict__ indptr, const int* __restrict__ csrc,
        TOUT* __restrict__ out, int N, int E) {
    constexpr int F = HEADS * 64;
    constexpr int TPW = (HEADS == 4) ? 4 : 1;
    constexpr int NITER = HEADS;
    constexpr float CSH = 5.0f;

    __shared__ f16 lh[HEADS * 4 * 512];
    __shared__ unsigned int af_s[32 * HEADS];
    __shared__ float er_s[16 * HEADS];
    __shared__ int iptr_s[17];

    int t = threadIdx.x;
    int wv = t >> 6, lane = t & 63;
    int n0 = blockIdx.x * 16;
    int head = (HEADS == 4) ? wv : 0;
    int n_ = lane & 15, kb = lane >> 4;
    int e_ = lane >> 1;

    if (t < 17) {
        int nn = n0 + t;
        iptr_s[t] = indptr[nn < N ? nn : N];
    }
    if (t < 16 * HEADS) {
        int nn = n0 + t / HEADS;
        er_s[t] = (nn < N) ? er[nn * HEADS + (t % HEADS)] : 0.f;
    }
    __syncthreads();
    int kbeg = iptr_s[0], kend = iptr_s[16];

    f32x4 acc[TPW];
#pragma unroll
    for (int i = 0; i < TPW; i++) acc[i] = (f32x4){0.f, 0.f, 0.f, 0.f};
    f32x4 acc_s = {0.f, 0.f, 0.f, 0.f};

    f16x8 bones;
#pragma unroll
    for (int i = 0; i < 8; i++) bones[i] = (f16)((n_ == 0) ? 1.f : 0.f);

    f16x8 rgA[NITER], rgB[NITER];
    unsigned int pkA = 0, pkB = 0;
    bool alane = (HEADS == 4 || wv == 0) && lane < 32;

    auto leaky = [](float v) { return v >= 0.f ? v : NEG_SLOPE * v; };

    // all loads independent; alpha math in registers (overlap region)
    auto issue = [&](int kb0, f16x8 (&rg)[NITER], unsigned int& pk) {
        int pos = kb0 + e_;
        int posc = pos < E ? pos : E - 1;
        const f16* row = h + (size_t)csrc[posc] * F;
#pragma unroll
        for (int i = 0; i < NITER; i++)
            rg[i] = *(const f16x8*)(row + 8 * (lane & 1) + 16 * i + 16 * NITER * wv);
        if (alane) {
            int p2 = kb0 + lane;
            int p2c = p2 < E ? p2 : E - 1;
            bool ok = p2 < kend;
            float ev = elg[(size_t)p2c * HEADS + head];
            unsigned int owner = 0;
#pragma unroll
            for (int i = 1; i < 16; i++) owner += (p2 >= iptr_s[i]) ? 1u : 0u;
            float lg = leaky(ev + er_s[owner * HEADS + head]);
            f16 w16 = (f16)__expf(lg - CSH);
            pk = ok ? ((owner << 16) | (unsigned int)__builtin_bit_cast(unsigned short, w16)) : 0u;
        }
    };

    auto dostep = [&](int kb0, f16x8 (&rg)[NITER], unsigned int& pk) {
        __syncthreads();   // prior compute done reading lh/af_s
#pragma unroll
        for (int i = 0; i < NITER; i++)
            *(f16x8*)&lh[(i + NITER * wv) * 512 + lane * 8] = rg[i];
        if (alane) af_s[lane * HEADS + head] = pk;
        __syncthreads();
        if (kb0 + 64 < kend) issue(kb0 + 64, rg, pk);   // consumed 2 steps later

        // A fragment: w[sigma(kb,jj)] masked by owner==n_
        union { unsigned int u[4]; f16x8 v; } afr;
#pragma unroll
        for (int jj = 0; jj < 8; jj++) {
            int e = (jj < 4) ? (kb * 4 + jj) : (16 + kb * 4 + (jj - 4));
            unsigned int v = af_s[e * HEADS + head];
            unsigned int ab = ((v >> 16) == (unsigned int)n_) ? (v & 0xffffu) : 0u;
            if (jj & 1) afr.u[jj >> 1] |= ab << 16;
            else        afr.u[jj >> 1] = ab;
        }

        // B fragments via hardware transpose read
        f16x4 b0[TPW], b1[TPW];
#pragma unroll
        for (int ti = 0; ti < TPW; ti++) {
            int tile = (HEADS == 4) ? ti : wv;
            unsigned int addr =
                (unsigned int)(size_t)&lh[(head * 4 + tile) * 512] + lane * 8;
            asm volatile("ds_read_b64_tr_b16 %0, %1" : "=v"(b0[ti]) : "v"(addr));
            asm volatile("ds_read_b64_tr_b16 %0, %1 offset:512" : "=v"(b1[ti]) : "v"(addr));
        }
        asm volatile("s_waitcnt lgkmcnt(0)");
        __builtin_amdgcn_sched_barrier(0);
#pragma unroll
        for (int ti = 0; ti < TPW; ti++) {
            f16x8 bfr = __builtin_shufflevector(b0[ti], b1[ti], 0, 1, 2, 3, 4, 5, 6, 7);
            acc[ti] = __builtin_amdgcn_mfma_f32_16x16x32_f16(afr.v, bfr, acc[ti], 0, 0, 0);
        }
        acc_s = __builtin_amdgcn_mfma_f32_16x16x32_f16(afr.v, bones, acc_s, 0, 0, 0);
    };

    if (kbeg < kend) issue(kbeg, rgA, pkA);
    if (kbeg + 32 < kend) issue(kbeg + 32, rgB, pkB);

    for (int k = kbeg; k < kend; k += 64) {
        dostep(k, rgA, pkA);
        if (k + 32 < kend) dostep(k + 32, rgB, pkB);
    }

    // denominator: s for row group kb sits in lane kb*16 (col 0)
    float sv[4];
#pragma unroll
    for (int r = 0; r < 4; r++) sv[r] = __shfl(acc_s[r], lane & 48);

    // epilogue: D row=(lane>>4)*4+r (node), col=lane&15 (feat)
#pragma unroll
    for (int ti = 0; ti < TPW; ti++) {
        int tile = (HEADS == 4) ? ti : wv;
        int col = head * 64 + tile * 16 + n_;
        float bv = bias[col];
#pragma unroll
        for (int r = 0; r < 4; r++) {
            int nn = n0 + kb * 4 + r;
            if (nn < N) {
                float inv = sv[r] > 0.f ? 1.f / sv[r] : 0.f;
                float v = acc[ti][r] * inv + bv;
                if (RELU) v = fmaxf(v, 0.f);
                out[(size_t)nn * F + col] = (TOUT)v;
            }
        }
    }
}

// ---------------- launch ----------------

extern "C" void kernel_launch(void* const* d_in, const int* in_sizes, int n_in,
                              void* d_out, int out_size, void* d_ws, size_t ws_size,
                              hipStream_t stream) {
    const float* x   = (const float*)d_in[0];
    const int*   src = (const int*)d_in[1];
    const int*   dst = (const int*)d_in[2];
    const float* W0  = (const float*)d_in[3];
    const float* al0 = (const float*)d_in[4];
    const float* ar0 = (const float*)d_in[5];
    const float* b0  = (const float*)d_in[6];
    const float* W1  = (const float*)d_in[7];
    const float* al1 = (const float*)d_in[8];
    const float* ar1 = (const float*)d_in[9];
    const float* b1  = (const float*)d_in[10];
    float* out = (float*)d_out;

    const int N = in_sizes[0] / 256;  // 50000
    const int E = in_sizes[1];        // 800000

    char* ws = (char*)d_ws;
    size_t off = 0;
    auto alloc = [&](size_t bytes) -> void* {
        void* p = ws + off;
        off += (bytes + 255) / 256 * 256;
        return p;
    };
    f16* h0        = (f16*)alloc((size_t)N * 256 * 2);
    f16* y         = (f16*)alloc((size_t)N * 256 * 2);
    f16* h1        = (f16*)alloc((size_t)N * 64 * 2);
    float* el0     = (float*)alloc((size_t)N * 4 * 4);
    float* er0     = (float*)alloc((size_t)N * 4 * 4);
    float* el1     = (float*)alloc((size_t)N * 4);
    float* er1     = (float*)alloc((size_t)N * 4);
    float* elg0    = (float*)alloc((size_t)E * 4 * 4);
    float* elg1    = (float*)alloc((size_t)E * 4);
    int* counts    = (int*)alloc((size_t)N * 4);
    int* indptr    = (int*)alloc((size_t)(N + 1) * 4);
    int* cursor    = (int*)alloc((size_t)N * 4);
    int* csrc      = (int*)alloc((size_t)E * 4);

    // ---- CSR build (by dst): 4 ops (was 7) ----
    hipMemsetAsync(counts, 0, (size_t)N * 4, stream);
    count_dst<<<(E + 255) / 256, 256, 0, stream>>>(dst, counts, E);
    scan_all<<<1, 1024, 0, stream>>>(counts, indptr, cursor, N, E);
    fill_csr<<<(E + 255) / 256, 256, 0, stream>>>(dst, src, cursor, csrc, E);

    int mtiles = (N + 63) / 64;   // 782
    int atiles = (N + 15) / 16;   // 3125
    int etiles = (E + 255) / 256; // 3125

    // ---- layer 0 ----
    gemm_mfma<256, float><<<mtiles, 256, 0, stream>>>(x, W0, h0, al0, ar0, el0, er0, N);
    elg_kernel<4><<<etiles, 256, 0, stream>>>(el0, csrc, elg0, E);
    agg_mfma<4, true, f16><<<atiles, 256, 0, stream>>>(h0, elg0, er0, b0, indptr, csrc, y, N, E);

    // ---- layer 1 ----
    gemm_mfma<64, f16><<<mtiles, 256, 0, stream>>>(y, W1, h1, al1, ar1, el1, er1, N);
    elg_kernel<1><<<etiles, 256, 0, stream>>>(el1, csrc, elg1, E);
    agg_mfma<1, false, float><<<atiles, 256, 0, stream>>>(h1, elg1, er1, b1, indptr, csrc, out, N, E);
}

// Round 11
// 268.879 us; speedup vs baseline: 1.3945x; 1.3945x over previous
//
#include <hip/hip_runtime.h>
#include <math.h>

#define NEG_SLOPE 0.2f

using f16   = _Float16;
using f16x4 = __attribute__((ext_vector_type(4))) _Float16;
using f16x8 = __attribute__((ext_vector_type(8))) _Float16;
using f32x4 = __attribute__((ext_vector_type(4))) float;

// ---------------- CSR build ----------------

__global__ void count_dst(const int* __restrict__ dst, int* __restrict__ counts, int E) {
    int e = blockIdx.x * blockDim.x + threadIdx.x;
    if (e < E) atomicAdd(&counts[dst[e]], 1);
}

// block 256 threads, 1024 elements per block: exclusive scan within block
__global__ void scan_local(const int* __restrict__ counts, int* __restrict__ indptr,
                           int* __restrict__ blocksums, int n) {
    __shared__ int sdata[256];
    int b = blockIdx.x, t = threadIdx.x;
    int base = b * 1024 + t * 4;
    int v[4];
    int sum = 0;
#pragma unroll
    for (int j = 0; j < 4; j++) {
        int idx = base + j;
        v[j] = (idx < n) ? counts[idx] : 0;
        sum += v[j];
    }
    sdata[t] = sum;
    __syncthreads();
    for (int o = 1; o < 256; o <<= 1) {
        int u = 0;
        if (t >= o) u = sdata[t - o];
        __syncthreads();
        if (t >= o) sdata[t] += u;
        __syncthreads();
    }
    int excl = (t > 0) ? sdata[t - 1] : 0;
    int run = excl;
#pragma unroll
    for (int j = 0; j < 4; j++) {
        int idx = base + j;
        if (idx < n) indptr[idx] = run;
        run += v[j];
    }
    if (t == 255) blocksums[b] = sdata[255];
}

__global__ void scan_carry(int* __restrict__ blocksums, int nb) {
    int t = threadIdx.x;
    int v = (t < nb) ? blocksums[t] : 0;
    int orig = v;
#pragma unroll
    for (int o = 1; o < 64; o <<= 1) {
        int u = __shfl_up(v, o);
        if (t >= o) v += u;
    }
    if (t < nb) blocksums[t] = v - orig;
}

// adds carry; also writes cursor (replaces the d2d memcpy)
__global__ void scan_add(int* __restrict__ indptr, int* __restrict__ cursor,
                         const int* __restrict__ blocksums, int n, int Etot) {
    int b = blockIdx.x, t = threadIdx.x;
    int base = b * 1024 + t * 4;
    int add = blocksums[b];
#pragma unroll
    for (int j = 0; j < 4; j++) {
        int idx = base + j;
        if (idx < n) {
            int v = indptr[idx] + add;
            indptr[idx] = v;
            cursor[idx] = v;
        }
    }
    if (b == 0 && t == 0) indptr[n] = Etot;
}

__global__ void fill_csr(const int* __restrict__ dst, const int* __restrict__ src,
                         int* __restrict__ cursor, int* __restrict__ csrc, int E) {
    int e = blockIdx.x * blockDim.x + threadIdx.x;
    if (e < E) {
        int p = atomicAdd(&cursor[dst[e]], 1);
        csrc[p] = src[e];
    }
}

// ---------------- edge el gather: elg[pos][h] = el[csrc[pos]][h] ----------------
// Dedicated kernel: the dependent random gather runs with full TLP (no
// barriers), so its latency is hidden by parallelism. agg then loads elg
// coalesced + independent (the R6/R9-fast property).

template <int HEADS>
__global__ __launch_bounds__(256) void elg_kernel(const float* __restrict__ el,
                                                  const int* __restrict__ csrc,
                                                  float* __restrict__ elg, int E) {
    int i = blockIdx.x * blockDim.x + threadIdx.x;
    if (i < E) {
        int sd = csrc[i];
        if constexpr (HEADS == 4)
            *(float4*)&elg[(size_t)i * 4] = *(const float4*)&el[(size_t)sd * 4];
        else
            elg[i] = el[sd];
    }
}

// ---------------- f16-MFMA GEMM + fused el/er ----------------
// C[M][BN] = A[M][256] * B[BN][256]^T (f16 out). Wave wn owns cols
// [64wn,64wn+64) = head wn, so el[row][wn] = sum(acc*al[col]) via 16-lane
// shfl reduce in the epilogue (saves a separate pass over h).

template <int BN, typename TA>
__global__ __launch_bounds__(256) void gemm_mfma(const TA* __restrict__ A,
                                                 const float* __restrict__ B,
                                                 f16* __restrict__ C,
                                                 const float* __restrict__ al,
                                                 const float* __restrict__ ar,
                                                 float* __restrict__ el,
                                                 float* __restrict__ er, int M) {
    constexpr int K = 256;
    constexpr int WAVES_N = BN / 64;
    constexpr int WAVES_M = 4 / WAVES_N;
    constexpr int WM = 64 / WAVES_M;
    constexpr int MF = WM / 16;

    __shared__ f16 as[64][40];
    __shared__ f16 bs[BN][40];

    int t = threadIdx.x;
    int wave = t >> 6, lane = t & 63;
    int wn = wave / WAVES_M;
    int wm = wave % WAVES_M;
    int row0 = blockIdx.x * 64;

    int srow = t >> 2;
    int skq = (t & 3) * 8;

    int lrow = lane & 15;
    int ksel = (lane >> 4) * 8;

    f32x4 acc[MF][4] = {};

    for (int k0 = 0; k0 < K; k0 += 32) {
        {
            int gr = row0 + srow;
            gr = gr < M ? gr : M - 1;
            if constexpr (sizeof(TA) == 4) {
                const float4* pa = (const float4*)(A + (size_t)gr * K + k0 + skq);
                float4 u0 = pa[0], u1 = pa[1];
                f16x8 av;
                av[0] = (f16)u0.x; av[1] = (f16)u0.y; av[2] = (f16)u0.z; av[3] = (f16)u0.w;
                av[4] = (f16)u1.x; av[5] = (f16)u1.y; av[6] = (f16)u1.z; av[7] = (f16)u1.w;
                *(f16x8*)&as[srow][skq] = av;
            } else {
                *(f16x8*)&as[srow][skq] = *(const f16x8*)(A + (size_t)gr * K + k0 + skq);
            }
        }
#pragma unroll
        for (int i = 0; i < BN / 64; i++) {
            int n = i * 64 + srow;
            const float4* pb = (const float4*)(B + (size_t)n * K + k0 + skq);
            float4 u0 = pb[0], u1 = pb[1];
            f16x8 bv;
            bv[0] = (f16)u0.x; bv[1] = (f16)u0.y; bv[2] = (f16)u0.z; bv[3] = (f16)u0.w;
            bv[4] = (f16)u1.x; bv[5] = (f16)u1.y; bv[6] = (f16)u1.z; bv[7] = (f16)u1.w;
            *(f16x8*)&bs[n][skq] = bv;
        }
        __syncthreads();

        f16x8 af[MF], bf[4];
#pragma unroll
        for (int i = 0; i < MF; i++)
            af[i] = *(const f16x8*)&as[wm * WM + i * 16 + lrow][ksel];
#pragma unroll
        for (int j = 0; j < 4; j++)
            bf[j] = *(const f16x8*)&bs[wn * 64 + j * 16 + lrow][ksel];
#pragma unroll
        for (int i = 0; i < MF; i++)
#pragma unroll
            for (int j = 0; j < 4; j++)
                acc[i][j] = __builtin_amdgcn_mfma_f32_16x16x32_f16(af[i], bf[j], acc[i][j], 0, 0, 0);
        __syncthreads();
    }

    // C store
#pragma unroll
    for (int i = 0; i < MF; i++) {
        int r0 = row0 + wm * WM + i * 16 + (lane >> 4) * 4;
#pragma unroll
        for (int j = 0; j < 4; j++) {
            int col = wn * 64 + j * 16 + (lane & 15);
#pragma unroll
            for (int r = 0; r < 4; r++) {
                int gr = r0 + r;
                if (gr < M) C[(size_t)gr * BN + col] = (f16)acc[i][j][r];
            }
        }
    }

    // fused el/er (head = wn)
#pragma unroll
    for (int i = 0; i < MF; i++) {
        float ea[4] = {}, eb[4] = {};
#pragma unroll
        for (int j = 0; j < 4; j++) {
            int col = wn * 64 + j * 16 + (lane & 15);
            float av = al[col], rv = ar[col];
#pragma unroll
            for (int r = 0; r < 4; r++) {
                ea[r] += acc[i][j][r] * av;
                eb[r] += acc[i][j][r] * rv;
            }
        }
#pragma unroll
        for (int o = 1; o <= 8; o <<= 1) {
#pragma unroll
            for (int r = 0; r < 4; r++) {
                ea[r] += __shfl_xor(ea[r], o);
                eb[r] += __shfl_xor(eb[r], o);
            }
        }
        if ((lane & 15) == 0) {
            int r0 = row0 + wm * WM + i * 16 + (lane >> 4) * 4;
#pragma unroll
            for (int r = 0; r < 4; r++) {
                int gr = r0 + r;
                if (gr < M) {
                    el[gr * WAVES_N + wn] = ea[r];
                    er[gr * WAVES_N + wn] = eb[r];
                }
            }
        }
    }
}

// ---------------- fused MFMA segment aggregation ----------------
// Block = 16 consecutive dst nodes. Per 32-edge K-step:
//  C[16n][D] += A[16n][32e] x H[32e][D], A[n][e] = w_e (owner-masked),
//  w_e = exp(leaky(elg[pos][h]+er[dst][h]) - CSH)  [unnormalized].
// Denominator via extra MFMA with B = ones column 0; divide in epilogue.
// issue(): rg gathers + elg load -- ALL independent loads (R9 property).
// 2-deep prefetch: named rgA/rgB + pkA/pkB; a buffer refilled in dostep(k)
// is consumed at dostep(k+64) -> ~2 steps (~500cy) of latency cover.
// dostep barrier section: pure LDS writes.
// Staging map: lane l, wave w, iter i -> LDS elem (i+NITER*w)*512 + 8l
// (linear per instruction: 0 write conflicts); layout matches tr_read.
// K-perm sigma(kb,j): j<4 -> 4*kb+j ; j>=4 -> 16+4*kb+(j-4); A uses same sigma.

template <int HEADS, bool RELU, typename TOUT>
__global__ __launch_bounds__(256) void agg_mfma(
        const f16* __restrict__ h, const float* __restrict__ elg,
        const float* __restrict__ er, const float* __restrict__ bias,
        const int* __restrict__ indptr, const int* __restrict__ csrc,
        TOUT* __restrict__ out, int N, int E) {
    constexpr int F = HEADS * 64;
    constexpr int TPW = (HEADS == 4) ? 4 : 1;
    constexpr int NITER = HEADS;
    constexpr float CSH = 5.0f;

    __shared__ f16 lh[HEADS * 4 * 512];
    __shared__ unsigned int af_s[32 * HEADS];
    __shared__ float er_s[16 * HEADS];
    __shared__ int iptr_s[17];

    int t = threadIdx.x;
    int wv = t >> 6, lane = t & 63;
    int n0 = blockIdx.x * 16;
    int head = (HEADS == 4) ? wv : 0;
    int n_ = lane & 15, kb = lane >> 4;
    int e_ = lane >> 1;

    if (t < 17) {
        int nn = n0 + t;
        iptr_s[t] = indptr[nn < N ? nn : N];
    }
    if (t < 16 * HEADS) {
        int nn = n0 + t / HEADS;
        er_s[t] = (nn < N) ? er[nn * HEADS + (t % HEADS)] : 0.f;
    }
    __syncthreads();
    int kbeg = iptr_s[0], kend = iptr_s[16];

    f32x4 acc[TPW];
#pragma unroll
    for (int i = 0; i < TPW; i++) acc[i] = (f32x4){0.f, 0.f, 0.f, 0.f};
    f32x4 acc_s = {0.f, 0.f, 0.f, 0.f};

    f16x8 bones;
#pragma unroll
    for (int i = 0; i < 8; i++) bones[i] = (f16)((n_ == 0) ? 1.f : 0.f);

    f16x8 rgA[NITER], rgB[NITER];
    unsigned int pkA = 0, pkB = 0;
    bool alane = (HEADS == 4 || wv == 0) && lane < 32;

    auto leaky = [](float v) { return v >= 0.f ? v : NEG_SLOPE * v; };

    // all loads independent; alpha math in registers (overlap region)
    auto issue = [&](int kb0, f16x8 (&rg)[NITER], unsigned int& pk) {
        int pos = kb0 + e_;
        int posc = pos < E ? pos : E - 1;
        const f16* row = h + (size_t)csrc[posc] * F;
#pragma unroll
        for (int i = 0; i < NITER; i++)
            rg[i] = *(const f16x8*)(row + 8 * (lane & 1) + 16 * i + 16 * NITER * wv);
        if (alane) {
            int p2 = kb0 + lane;
            int p2c = p2 < E ? p2 : E - 1;
            bool ok = p2 < kend;
            float ev = elg[(size_t)p2c * HEADS + head];
            unsigned int owner = 0;
#pragma unroll
            for (int i = 1; i < 16; i++) owner += (p2 >= iptr_s[i]) ? 1u : 0u;
            float lg = leaky(ev + er_s[owner * HEADS + head]);
            f16 w16 = (f16)__expf(lg - CSH);
            pk = ok ? ((owner << 16) | (unsigned int)__builtin_bit_cast(unsigned short, w16)) : 0u;
        }
    };

    auto dostep = [&](int kb0, f16x8 (&rg)[NITER], unsigned int& pk) {
        __syncthreads();   // prior compute done reading lh/af_s
#pragma unroll
        for (int i = 0; i < NITER; i++)
            *(f16x8*)&lh[(i + NITER * wv) * 512 + lane * 8] = rg[i];
        if (alane) af_s[lane * HEADS + head] = pk;
        __syncthreads();
        if (kb0 + 64 < kend) issue(kb0 + 64, rg, pk);   // consumed 2 steps later

        // A fragment: w[sigma(kb,jj)] masked by owner==n_
        union { unsigned int u[4]; f16x8 v; } afr;
#pragma unroll
        for (int jj = 0; jj < 8; jj++) {
            int e = (jj < 4) ? (kb * 4 + jj) : (16 + kb * 4 + (jj - 4));
            unsigned int v = af_s[e * HEADS + head];
            unsigned int ab = ((v >> 16) == (unsigned int)n_) ? (v & 0xffffu) : 0u;
            if (jj & 1) afr.u[jj >> 1] |= ab << 16;
            else        afr.u[jj >> 1] = ab;
        }

        // B fragments via hardware transpose read
        f16x4 b0[TPW], b1[TPW];
#pragma unroll
        for (int ti = 0; ti < TPW; ti++) {
            int tile = (HEADS == 4) ? ti : wv;
            unsigned int addr =
                (unsigned int)(size_t)&lh[(head * 4 + tile) * 512] + lane * 8;
            asm volatile("ds_read_b64_tr_b16 %0, %1" : "=v"(b0[ti]) : "v"(addr));
            asm volatile("ds_read_b64_tr_b16 %0, %1 offset:512" : "=v"(b1[ti]) : "v"(addr));
        }
        asm volatile("s_waitcnt lgkmcnt(0)");
        __builtin_amdgcn_sched_barrier(0);
#pragma unroll
        for (int ti = 0; ti < TPW; ti++) {
            f16x8 bfr = __builtin_shufflevector(b0[ti], b1[ti], 0, 1, 2, 3, 4, 5, 6, 7);
            acc[ti] = __builtin_amdgcn_mfma_f32_16x16x32_f16(afr.v, bfr, acc[ti], 0, 0, 0);
        }
        acc_s = __builtin_amdgcn_mfma_f32_16x16x32_f16(afr.v, bones, acc_s, 0, 0, 0);
    };

    if (kbeg < kend) issue(kbeg, rgA, pkA);
    if (kbeg + 32 < kend) issue(kbeg + 32, rgB, pkB);

    for (int k = kbeg; k < kend; k += 64) {
        dostep(k, rgA, pkA);
        if (k + 32 < kend) dostep(k + 32, rgB, pkB);
    }

    // denominator: s for row group kb sits in lane kb*16 (col 0)
    float sv[4];
#pragma unroll
    for (int r = 0; r < 4; r++) sv[r] = __shfl(acc_s[r], lane & 48);

    // epilogue: D row=(lane>>4)*4+r (node), col=lane&15 (feat)
#pragma unroll
    for (int ti = 0; ti < TPW; ti++) {
        int tile = (HEADS == 4) ? ti : wv;
        int col = head * 64 + tile * 16 + n_;
        float bv = bias[col];
#pragma unroll
        for (int r = 0; r < 4; r++) {
            int nn = n0 + kb * 4 + r;
            if (nn < N) {
                float inv = sv[r] > 0.f ? 1.f / sv[r] : 0.f;
                float v = acc[ti][r] * inv + bv;
                if (RELU) v = fmaxf(v, 0.f);
                out[(size_t)nn * F + col] = (TOUT)v;
            }
        }
    }
}

// ---------------- launch ----------------

extern "C" void kernel_launch(void* const* d_in, const int* in_sizes, int n_in,
                              void* d_out, int out_size, void* d_ws, size_t ws_size,
                              hipStream_t stream) {
    const float* x   = (const float*)d_in[0];
    const int*   src = (const int*)d_in[1];
    const int*   dst = (const int*)d_in[2];
    const float* W0  = (const float*)d_in[3];
    const float* al0 = (const float*)d_in[4];
    const float* ar0 = (const float*)d_in[5];
    const float* b0  = (const float*)d_in[6];
    const float* W1  = (const float*)d_in[7];
    const float* al1 = (const float*)d_in[8];
    const float* ar1 = (const float*)d_in[9];
    const float* b1  = (const float*)d_in[10];
    float* out = (float*)d_out;

    const int N = in_sizes[0] / 256;  // 50000
    const int E = in_sizes[1];        // 800000

    char* ws = (char*)d_ws;
    size_t off = 0;
    auto alloc = [&](size_t bytes) -> void* {
        void* p = ws + off;
        off += (bytes + 255) / 256 * 256;
        return p;
    };
    f16* h0        = (f16*)alloc((size_t)N * 256 * 2);
    f16* y         = (f16*)alloc((size_t)N * 256 * 2);
    f16* h1        = (f16*)alloc((size_t)N * 64 * 2);
    float* el0     = (float*)alloc((size_t)N * 4 * 4);
    float* er0     = (float*)alloc((size_t)N * 4 * 4);
    float* el1     = (float*)alloc((size_t)N * 4);
    float* er1     = (float*)alloc((size_t)N * 4);
    float* elg0    = (float*)alloc((size_t)E * 4 * 4);
    float* elg1    = (float*)alloc((size_t)E * 4);
    int* counts    = (int*)alloc((size_t)N * 4);
    int* indptr    = (int*)alloc((size_t)(N + 1) * 4);
    int* cursor    = (int*)alloc((size_t)N * 4);
    int* csrc      = (int*)alloc((size_t)E * 4);
    int* blocksums = (int*)alloc(64 * 4);

    // ---- CSR build (by dst): multi-block scan (R9 structure, no memcpy) ----
    hipMemsetAsync(counts, 0, (size_t)N * 4, stream);
    count_dst<<<(E + 255) / 256, 256, 0, stream>>>(dst, counts, E);
    int nb = (N + 1023) / 1024;  // 49
    scan_local<<<nb, 256, 0, stream>>>(counts, indptr, blocksums, N);
    scan_carry<<<1, 64, 0, stream>>>(blocksums, nb);
    scan_add<<<nb, 256, 0, stream>>>(indptr, cursor, blocksums, N, E);
    fill_csr<<<(E + 255) / 256, 256, 0, stream>>>(dst, src, cursor, csrc, E);

    int mtiles = (N + 63) / 64;   // 782
    int atiles = (N + 15) / 16;   // 3125
    int etiles = (E + 255) / 256; // 3125

    // ---- layer 0 ----
    gemm_mfma<256, float><<<mtiles, 256, 0, stream>>>(x, W0, h0, al0, ar0, el0, er0, N);
    elg_kernel<4><<<etiles, 256, 0, stream>>>(el0, csrc, elg0, E);
    agg_mfma<4, true, f16><<<atiles, 256, 0, stream>>>(h0, elg0, er0, b0, indptr, csrc, y, N, E);

    // ---- layer 1 ----
    gemm_mfma<64, f16><<<mtiles, 256, 0, stream>>>(y, W1, h1, al1, ar1, el1, er1, N);
    elg_kernel<1><<<etiles, 256, 0, stream>>>(el1, csrc, elg1, E);
    agg_mfma<1, false, float><<<(N + 15) / 16, 256, 0, stream>>>(h1, elg1, er1, b1, indptr, csrc, out, N, E);
}

// Round 12
// 260.508 us; speedup vs baseline: 1.4393x; 1.0321x over previous
//
#include <hip/hip_runtime.h>
#include <math.h>

#define NEG_SLOPE 0.2f

using f16   = _Float16;
using f16x4 = __attribute__((ext_vector_type(4))) _Float16;
using f16x8 = __attribute__((ext_vector_type(8))) _Float16;
using f32x4 = __attribute__((ext_vector_type(4))) float;

// ---------------- CSR build ----------------

__global__ void count_dst(const int* __restrict__ dst, int* __restrict__ counts, int E) {
    int e = blockIdx.x * blockDim.x + threadIdx.x;
    if (e < E) atomicAdd(&counts[dst[e]], 1);
}

// block 256 threads, 1024 elements per block: exclusive scan within block
__global__ void scan_local(const int* __restrict__ counts, int* __restrict__ indptr,
                           int* __restrict__ blocksums, int n) {
    __shared__ int sdata[256];
    int b = blockIdx.x, t = threadIdx.x;
    int base = b * 1024 + t * 4;
    int v[4];
    int sum = 0;
#pragma unroll
    for (int j = 0; j < 4; j++) {
        int idx = base + j;
        v[j] = (idx < n) ? counts[idx] : 0;
        sum += v[j];
    }
    sdata[t] = sum;
    __syncthreads();
    for (int o = 1; o < 256; o <<= 1) {
        int u = 0;
        if (t >= o) u = sdata[t - o];
        __syncthreads();
        if (t >= o) sdata[t] += u;
        __syncthreads();
    }
    int excl = (t > 0) ? sdata[t - 1] : 0;
    int run = excl;
#pragma unroll
    for (int j = 0; j < 4; j++) {
        int idx = base + j;
        if (idx < n) indptr[idx] = run;
        run += v[j];
    }
    if (t == 255) blocksums[b] = sdata[255];
}

__global__ void scan_carry(int* __restrict__ blocksums, int nb) {
    int t = threadIdx.x;
    int v = (t < nb) ? blocksums[t] : 0;
    int orig = v;
#pragma unroll
    for (int o = 1; o < 64; o <<= 1) {
        int u = __shfl_up(v, o);
        if (t >= o) v += u;
    }
    if (t < nb) blocksums[t] = v - orig;
}

// adds carry; also writes cursor (replaces the d2d memcpy)
__global__ void scan_add(int* __restrict__ indptr, int* __restrict__ cursor,
                         const int* __restrict__ blocksums, int n, int Etot) {
    int b = blockIdx.x, t = threadIdx.x;
    int base = b * 1024 + t * 4;
    int add = blocksums[b];
#pragma unroll
    for (int j = 0; j < 4; j++) {
        int idx = base + j;
        if (idx < n) {
            int v = indptr[idx] + add;
            indptr[idx] = v;
            cursor[idx] = v;
        }
    }
    if (b == 0 && t == 0) indptr[n] = Etot;
}

__global__ void fill_csr(const int* __restrict__ dst, const int* __restrict__ src,
                         int* __restrict__ cursor, int* __restrict__ csrc, int E) {
    int e = blockIdx.x * blockDim.x + threadIdx.x;
    if (e < E) {
        int p = atomicAdd(&cursor[dst[e]], 1);
        csrc[p] = src[e];
    }
}

// ---------------- edge el gather: elg[pos][h] = el[csrc[pos]][h] ----------------
// Dedicated kernel: the dependent random gather runs with full TLP (no
// barriers), so its latency is hidden by parallelism. agg then loads elg
// coalesced + independent (the R6/R9-fast property).

template <int HEADS>
__global__ __launch_bounds__(256) void elg_kernel(const float* __restrict__ el,
                                                  const int* __restrict__ csrc,
                                                  float* __restrict__ elg, int E) {
    int i = blockIdx.x * blockDim.x + threadIdx.x;
    if (i < E) {
        int sd = csrc[i];
        if constexpr (HEADS == 4)
            *(float4*)&elg[(size_t)i * 4] = *(const float4*)&el[(size_t)sd * 4];
        else
            elg[i] = el[sd];
    }
}

// ---------------- f16-MFMA GEMM + fused el/er ----------------
// C[M][BN] = A[M][256] * B[BN][256]^T (f16 out). Wave wn owns cols
// [64wn,64wn+64) = head wn, so el[row][wn] = sum(acc*al[col]) via 16-lane
// shfl reduce in the epilogue (saves a separate pass over h).

template <int BN, typename TA>
__global__ __launch_bounds__(256) void gemm_mfma(const TA* __restrict__ A,
                                                 const float* __restrict__ B,
                                                 f16* __restrict__ C,
                                                 const float* __restrict__ al,
                                                 const float* __restrict__ ar,
                                                 float* __restrict__ el,
                                                 float* __restrict__ er, int M) {
    constexpr int K = 256;
    constexpr int WAVES_N = BN / 64;
    constexpr int WAVES_M = 4 / WAVES_N;
    constexpr int WM = 64 / WAVES_M;
    constexpr int MF = WM / 16;

    __shared__ f16 as[64][40];
    __shared__ f16 bs[BN][40];

    int t = threadIdx.x;
    int wave = t >> 6, lane = t & 63;
    int wn = wave / WAVES_M;
    int wm = wave % WAVES_M;
    int row0 = blockIdx.x * 64;

    int srow = t >> 2;
    int skq = (t & 3) * 8;

    int lrow = lane & 15;
    int ksel = (lane >> 4) * 8;

    f32x4 acc[MF][4] = {};

    for (int k0 = 0; k0 < K; k0 += 32) {
        {
            int gr = row0 + srow;
            gr = gr < M ? gr : M - 1;
            if constexpr (sizeof(TA) == 4) {
                const float4* pa = (const float4*)(A + (size_t)gr * K + k0 + skq);
                float4 u0 = pa[0], u1 = pa[1];
                f16x8 av;
                av[0] = (f16)u0.x; av[1] = (f16)u0.y; av[2] = (f16)u0.z; av[3] = (f16)u0.w;
                av[4] = (f16)u1.x; av[5] = (f16)u1.y; av[6] = (f16)u1.z; av[7] = (f16)u1.w;
                *(f16x8*)&as[srow][skq] = av;
            } else {
                *(f16x8*)&as[srow][skq] = *(const f16x8*)(A + (size_t)gr * K + k0 + skq);
            }
        }
#pragma unroll
        for (int i = 0; i < BN / 64; i++) {
            int n = i * 64 + srow;
            const float4* pb = (const float4*)(B + (size_t)n * K + k0 + skq);
            float4 u0 = pb[0], u1 = pb[1];
            f16x8 bv;
            bv[0] = (f16)u0.x; bv[1] = (f16)u0.y; bv[2] = (f16)u0.z; bv[3] = (f16)u0.w;
            bv[4] = (f16)u1.x; bv[5] = (f16)u1.y; bv[6] = (f16)u1.z; bv[7] = (f16)u1.w;
            *(f16x8*)&bs[n][skq] = bv;
        }
        __syncthreads();

        f16x8 af[MF], bf[4];
#pragma unroll
        for (int i = 0; i < MF; i++)
            af[i] = *(const f16x8*)&as[wm * WM + i * 16 + lrow][ksel];
#pragma unroll
        for (int j = 0; j < 4; j++)
            bf[j] = *(const f16x8*)&bs[wn * 64 + j * 16 + lrow][ksel];
#pragma unroll
        for (int i = 0; i < MF; i++)
#pragma unroll
            for (int j = 0; j < 4; j++)
                acc[i][j] = __builtin_amdgcn_mfma_f32_16x16x32_f16(af[i], bf[j], acc[i][j], 0, 0, 0);
        __syncthreads();
    }

    // C store
#pragma unroll
    for (int i = 0; i < MF; i++) {
        int r0 = row0 + wm * WM + i * 16 + (lane >> 4) * 4;
#pragma unroll
        for (int j = 0; j < 4; j++) {
            int col = wn * 64 + j * 16 + (lane & 15);
#pragma unroll
            for (int r = 0; r < 4; r++) {
                int gr = r0 + r;
                if (gr < M) C[(size_t)gr * BN + col] = (f16)acc[i][j][r];
            }
        }
    }

    // fused el/er (head = wn)
#pragma unroll
    for (int i = 0; i < MF; i++) {
        float ea[4] = {}, eb[4] = {};
#pragma unroll
        for (int j = 0; j < 4; j++) {
            int col = wn * 64 + j * 16 + (lane & 15);
            float av = al[col], rv = ar[col];
#pragma unroll
            for (int r = 0; r < 4; r++) {
                ea[r] += acc[i][j][r] * av;
                eb[r] += acc[i][j][r] * rv;
            }
        }
#pragma unroll
        for (int o = 1; o <= 8; o <<= 1) {
#pragma unroll
            for (int r = 0; r < 4; r++) {
                ea[r] += __shfl_xor(ea[r], o);
                eb[r] += __shfl_xor(eb[r], o);
            }
        }
        if ((lane & 15) == 0) {
            int r0 = row0 + wm * WM + i * 16 + (lane >> 4) * 4;
#pragma unroll
            for (int r = 0; r < 4; r++) {
                int gr = r0 + r;
                if (gr < M) {
                    el[gr * WAVES_N + wn] = ea[r];
                    er[gr * WAVES_N + wn] = eb[r];
                }
            }
        }
    }
}

// ---------------- fused MFMA segment aggregation ----------------
// Block = 16 consecutive dst nodes. Per 32-edge K-step:
//  C[16n][D] += A[16n][32e] x H[32e][D], A[n][e] = w_e (owner-masked),
//  w_e = exp(leaky(elg[pos][h]+er[dst][h]) - CSH)  [unnormalized].
// Denominator via extra MFMA with B = ones column 0; divide in epilogue.
// issue(): rg gathers + elg load -- ALL independent loads (R9 property).
// 1-deep prefetch (R9 measured-best: 44 VGPR, occupancy ~43%; R11 showed
// 2-deep costs 20 VGPR -> occupancy 35% -> NET LOSS; TLP is the latency
// hider here, don't trade it for ILP).
// dostep barrier section: pure LDS writes.
// Staging map: lane l, wave w, iter i -> LDS elem (i+NITER*w)*512 + 8l
// (linear per instruction: 0 write conflicts); layout matches tr_read.
// K-perm sigma(kb,j): j<4 -> 4*kb+j ; j>=4 -> 16+4*kb+(j-4); A uses same sigma.

template <int HEADS, bool RELU, typename TOUT>
__global__ __launch_bounds__(256) void agg_mfma(
        const f16* __restrict__ h, const float* __restrict__ elg,
        const float* __restrict__ er, const float* __restrict__ bias,
        const int* __restrict__ indptr, const int* __restrict__ csrc,
        TOUT* __restrict__ out, int N, int E) {
    constexpr int F = HEADS * 64;
    constexpr int TPW = (HEADS == 4) ? 4 : 1;
    constexpr int NITER = HEADS;
    constexpr float CSH = 5.0f;

    __shared__ f16 lh[HEADS * 4 * 512];
    __shared__ unsigned int af_s[32 * HEADS];
    __shared__ float er_s[16 * HEADS];
    __shared__ int iptr_s[17];

    int t = threadIdx.x;
    int wv = t >> 6, lane = t & 63;
    int n0 = blockIdx.x * 16;
    int head = (HEADS == 4) ? wv : 0;
    int n_ = lane & 15, kb = lane >> 4;
    int e_ = lane >> 1;

    if (t < 17) {
        int nn = n0 + t;
        iptr_s[t] = indptr[nn < N ? nn : N];
    }
    if (t < 16 * HEADS) {
        int nn = n0 + t / HEADS;
        er_s[t] = (nn < N) ? er[nn * HEADS + (t % HEADS)] : 0.f;
    }
    __syncthreads();
    int kbeg = iptr_s[0], kend = iptr_s[16];

    f32x4 acc[TPW];
#pragma unroll
    for (int i = 0; i < TPW; i++) acc[i] = (f32x4){0.f, 0.f, 0.f, 0.f};
    f32x4 acc_s = {0.f, 0.f, 0.f, 0.f};

    f16x8 bones;
#pragma unroll
    for (int i = 0; i < 8; i++) bones[i] = (f16)((n_ == 0) ? 1.f : 0.f);

    f16x8 rg[NITER];
    unsigned int pk = 0;
    bool alane = (HEADS == 4 || wv == 0) && lane < 32;

    auto leaky = [](float v) { return v >= 0.f ? v : NEG_SLOPE * v; };

    // all loads independent; alpha math in registers (overlap region)
    auto issue = [&](int kb0) {
        int pos = kb0 + e_;
        int posc = pos < E ? pos : E - 1;
        const f16* row = h + (size_t)csrc[posc] * F;
#pragma unroll
        for (int i = 0; i < NITER; i++)
            rg[i] = *(const f16x8*)(row + 8 * (lane & 1) + 16 * i + 16 * NITER * wv);
        if (alane) {
            int p2 = kb0 + lane;
            int p2c = p2 < E ? p2 : E - 1;
            bool ok = p2 < kend;
            float ev = elg[(size_t)p2c * HEADS + head];
            unsigned int owner = 0;
#pragma unroll
            for (int i = 1; i < 16; i++) owner += (p2 >= iptr_s[i]) ? 1u : 0u;
            float lg = leaky(ev + er_s[owner * HEADS + head]);
            f16 w16 = (f16)__expf(lg - CSH);
            pk = ok ? ((owner << 16) | (unsigned int)__builtin_bit_cast(unsigned short, w16)) : 0u;
        }
    };

    auto dostep = [&](int kb0) {
        __syncthreads();   // prior compute done reading lh/af_s
#pragma unroll
        for (int i = 0; i < NITER; i++)
            *(f16x8*)&lh[(i + NITER * wv) * 512 + lane * 8] = rg[i];
        if (alane) af_s[lane * HEADS + head] = pk;
        __syncthreads();
        if (kb0 + 32 < kend) issue(kb0 + 32);   // refill, consumed next step

        // A fragment: w[sigma(kb,jj)] masked by owner==n_
        union { unsigned int u[4]; f16x8 v; } afr;
#pragma unroll
        for (int jj = 0; jj < 8; jj++) {
            int e = (jj < 4) ? (kb * 4 + jj) : (16 + kb * 4 + (jj - 4));
            unsigned int v = af_s[e * HEADS + head];
            unsigned int ab = ((v >> 16) == (unsigned int)n_) ? (v & 0xffffu) : 0u;
            if (jj & 1) afr.u[jj >> 1] |= ab << 16;
            else        afr.u[jj >> 1] = ab;
        }

        // B fragments via hardware transpose read
        f16x4 b0[TPW], b1[TPW];
#pragma unroll
        for (int ti = 0; ti < TPW; ti++) {
            int tile = (HEADS == 4) ? ti : wv;
            unsigned int addr =
                (unsigned int)(size_t)&lh[(head * 4 + tile) * 512] + lane * 8;
            asm volatile("ds_read_b64_tr_b16 %0, %1" : "=v"(b0[ti]) : "v"(addr));
            asm volatile("ds_read_b64_tr_b16 %0, %1 offset:512" : "=v"(b1[ti]) : "v"(addr));
        }
        asm volatile("s_waitcnt lgkmcnt(0)");
        __builtin_amdgcn_sched_barrier(0);
#pragma unroll
        for (int ti = 0; ti < TPW; ti++) {
            f16x8 bfr = __builtin_shufflevector(b0[ti], b1[ti], 0, 1, 2, 3, 4, 5, 6, 7);
            acc[ti] = __builtin_amdgcn_mfma_f32_16x16x32_f16(afr.v, bfr, acc[ti], 0, 0, 0);
        }
        acc_s = __builtin_amdgcn_mfma_f32_16x16x32_f16(afr.v, bones, acc_s, 0, 0, 0);
    };

    if (kbeg < kend) issue(kbeg);
    for (int k = kbeg; k < kend; k += 32) dostep(k);

    // denominator: s for row group kb sits in lane kb*16 (col 0)
    float sv[4];
#pragma unroll
    for (int r = 0; r < 4; r++) sv[r] = __shfl(acc_s[r], lane & 48);

    // epilogue: D row=(lane>>4)*4+r (node), col=lane&15 (feat)
#pragma unroll
    for (int ti = 0; ti < TPW; ti++) {
        int tile = (HEADS == 4) ? ti : wv;
        int col = head * 64 + tile * 16 + n_;
        float bv = bias[col];
#pragma unroll
        for (int r = 0; r < 4; r++) {
            int nn = n0 + kb * 4 + r;
            if (nn < N) {
                float inv = sv[r] > 0.f ? 1.f / sv[r] : 0.f;
                float v = acc[ti][r] * inv + bv;
                if (RELU) v = fmaxf(v, 0.f);
                out[(size_t)nn * F + col] = (TOUT)v;
            }
        }
    }
}

// ---------------- launch ----------------

extern "C" void kernel_launch(void* const* d_in, const int* in_sizes, int n_in,
                              void* d_out, int out_size, void* d_ws, size_t ws_size,
                              hipStream_t stream) {
    const float* x   = (const float*)d_in[0];
    const int*   src = (const int*)d_in[1];
    const int*   dst = (const int*)d_in[2];
    const float* W0  = (const float*)d_in[3];
    const float* al0 = (const float*)d_in[4];
    const float* ar0 = (const float*)d_in[5];
    const float* b0  = (const float*)d_in[6];
    const float* W1  = (const float*)d_in[7];
    const float* al1 = (const float*)d_in[8];
    const float* ar1 = (const float*)d_in[9];
    const float* b1  = (const float*)d_in[10];
    float* out = (float*)d_out;

    const int N = in_sizes[0] / 256;  // 50000
    const int E = in_sizes[1];        // 800000

    char* ws = (char*)d_ws;
    size_t off = 0;
    auto alloc = [&](size_t bytes) -> void* {
        void* p = ws + off;
        off += (bytes + 255) / 256 * 256;
        return p;
    };
    f16* h0        = (f16*)alloc((size_t)N * 256 * 2);
    f16* y         = (f16*)alloc((size_t)N * 256 * 2);
    f16* h1        = (f16*)alloc((size_t)N * 64 * 2);
    float* el0     = (float*)alloc((size_t)N * 4 * 4);
    float* er0     = (float*)alloc((size_t)N * 4 * 4);
    float* el1     = (float*)alloc((size_t)N * 4);
    float* er1     = (float*)alloc((size_t)N * 4);
    float* elg0    = (float*)alloc((size_t)E * 4 * 4);
    float* elg1    = (float*)alloc((size_t)E * 4);
    int* counts    = (int*)alloc((size_t)N * 4);
    int* indptr    = (int*)alloc((size_t)(N + 1) * 4);
    int* cursor    = (int*)alloc((size_t)N * 4);
    int* csrc      = (int*)alloc((size_t)E * 4);
    int* blocksums = (int*)alloc(64 * 4);

    // ---- CSR build (by dst): multi-block scan, no memcpy ----
    hipMemsetAsync(counts, 0, (size_t)N * 4, stream);
    count_dst<<<(E + 255) / 256, 256, 0, stream>>>(dst, counts, E);
    int nb = (N + 1023) / 1024;  // 49
    scan_local<<<nb, 256, 0, stream>>>(counts, indptr, blocksums, N);
    scan_carry<<<1, 64, 0, stream>>>(blocksums, nb);
    scan_add<<<nb, 256, 0, stream>>>(indptr, cursor, blocksums, N, E);
    fill_csr<<<(E + 255) / 256, 256, 0, stream>>>(dst, src, cursor, csrc, E);

    int mtiles = (N + 63) / 64;   // 782
    int atiles = (N + 15) / 16;   // 3125
    int etiles = (E + 255) / 256; // 3125

    // ---- layer 0 ----
    gemm_mfma<256, float><<<mtiles, 256, 0, stream>>>(x, W0, h0, al0, ar0, el0, er0, N);
    elg_kernel<4><<<etiles, 256, 0, stream>>>(el0, csrc, elg0, E);
    agg_mfma<4, true, f16><<<atiles, 256, 0, stream>>>(h0, elg0, er0, b0, indptr, csrc, y, N, E);

    // ---- layer 1 ----
    gemm_mfma<64, f16><<<mtiles, 256, 0, stream>>>(y, W1, h1, al1, ar1, el1, er1, N);
    elg_kernel<1><<<etiles, 256, 0, stream>>>(el1, csrc, elg1, E);
    agg_mfma<1, false, float><<<atiles, 256, 0, stream>>>(h1, elg1, er1, b1, indptr, csrc, out, N, E);
}

// Round 13
// 254.308 us; speedup vs baseline: 1.4744x; 1.0244x over previous
//
#include <hip/hip_runtime.h>
#include <math.h>

#define NEG_SLOPE 0.2f

using f16   = _Float16;
using f16x4 = __attribute__((ext_vector_type(4))) _Float16;
using f16x8 = __attribute__((ext_vector_type(8))) _Float16;
using f32x4 = __attribute__((ext_vector_type(4))) float;

// ---------------- CSR build ----------------

__global__ void count_dst(const int* __restrict__ dst, int* __restrict__ counts, int E) {
    int e = blockIdx.x * blockDim.x + threadIdx.x;
    if (e < E) atomicAdd(&counts[dst[e]], 1);
}

__global__ void scan_local(const int* __restrict__ counts, int* __restrict__ indptr,
                           int* __restrict__ blocksums, int n) {
    __shared__ int sdata[256];
    int b = blockIdx.x, t = threadIdx.x;
    int base = b * 1024 + t * 4;
    int v[4];
    int sum = 0;
#pragma unroll
    for (int j = 0; j < 4; j++) {
        int idx = base + j;
        v[j] = (idx < n) ? counts[idx] : 0;
        sum += v[j];
    }
    sdata[t] = sum;
    __syncthreads();
    for (int o = 1; o < 256; o <<= 1) {
        int u = 0;
        if (t >= o) u = sdata[t - o];
        __syncthreads();
        if (t >= o) sdata[t] += u;
        __syncthreads();
    }
    int excl = (t > 0) ? sdata[t - 1] : 0;
    int run = excl;
#pragma unroll
    for (int j = 0; j < 4; j++) {
        int idx = base + j;
        if (idx < n) indptr[idx] = run;
        run += v[j];
    }
    if (t == 255) blocksums[b] = sdata[255];
}

__global__ void scan_carry(int* __restrict__ blocksums, int nb) {
    int t = threadIdx.x;
    int v = (t < nb) ? blocksums[t] : 0;
    int orig = v;
#pragma unroll
    for (int o = 1; o < 64; o <<= 1) {
        int u = __shfl_up(v, o);
        if (t >= o) v += u;
    }
    if (t < nb) blocksums[t] = v - orig;
}

// adds carry; also writes cursor (replaces the d2d memcpy)
__global__ void scan_add(int* __restrict__ indptr, int* __restrict__ cursor,
                         const int* __restrict__ blocksums, int n, int Etot) {
    int b = blockIdx.x, t = threadIdx.x;
    int base = b * 1024 + t * 4;
    int add = blocksums[b];
#pragma unroll
    for (int j = 0; j < 4; j++) {
        int idx = base + j;
        if (idx < n) {
            int v = indptr[idx] + add;
            indptr[idx] = v;
            cursor[idx] = v;
        }
    }
    if (b == 0 && t == 0) indptr[n] = Etot;
}

__global__ void fill_csr(const int* __restrict__ dst, const int* __restrict__ src,
                         int* __restrict__ cursor, int* __restrict__ csrc, int E) {
    int e = blockIdx.x * blockDim.x + threadIdx.x;
    if (e < E) {
        int p = atomicAdd(&cursor[dst[e]], 1);
        csrc[p] = src[e];
    }
}

// ---------------- edge el gather: elg[pos][h] = el[csrc[pos]][h] ----------------

template <int HEADS>
__global__ __launch_bounds__(256) void elg_kernel(const float* __restrict__ el,
                                                  const int* __restrict__ csrc,
                                                  float* __restrict__ elg, int E) {
    int i = blockIdx.x * blockDim.x + threadIdx.x;
    if (i < E) {
        int sd = csrc[i];
        if constexpr (HEADS == 4)
            *(float4*)&elg[(size_t)i * 4] = *(const float4*)&el[(size_t)sd * 4];
        else
            elg[i] = el[sd];
    }
}

// ---------------- f16-MFMA GEMM + fused el/er ----------------

template <int BN, typename TA>
__global__ __launch_bounds__(256) void gemm_mfma(const TA* __restrict__ A,
                                                 const float* __restrict__ B,
                                                 f16* __restrict__ C,
                                                 const float* __restrict__ al,
                                                 const float* __restrict__ ar,
                                                 float* __restrict__ el,
                                                 float* __restrict__ er, int M) {
    constexpr int K = 256;
    constexpr int WAVES_N = BN / 64;
    constexpr int WAVES_M = 4 / WAVES_N;
    constexpr int WM = 64 / WAVES_M;
    constexpr int MF = WM / 16;

    __shared__ f16 as[64][40];
    __shared__ f16 bs[BN][40];

    int t = threadIdx.x;
    int wave = t >> 6, lane = t & 63;
    int wn = wave / WAVES_M;
    int wm = wave % WAVES_M;
    int row0 = blockIdx.x * 64;

    int srow = t >> 2;
    int skq = (t & 3) * 8;

    int lrow = lane & 15;
    int ksel = (lane >> 4) * 8;

    f32x4 acc[MF][4] = {};

    for (int k0 = 0; k0 < K; k0 += 32) {
        {
            int gr = row0 + srow;
            gr = gr < M ? gr : M - 1;
            if constexpr (sizeof(TA) == 4) {
                const float4* pa = (const float4*)(A + (size_t)gr * K + k0 + skq);
                float4 u0 = pa[0], u1 = pa[1];
                f16x8 av;
                av[0] = (f16)u0.x; av[1] = (f16)u0.y; av[2] = (f16)u0.z; av[3] = (f16)u0.w;
                av[4] = (f16)u1.x; av[5] = (f16)u1.y; av[6] = (f16)u1.z; av[7] = (f16)u1.w;
                *(f16x8*)&as[srow][skq] = av;
            } else {
                *(f16x8*)&as[srow][skq] = *(const f16x8*)(A + (size_t)gr * K + k0 + skq);
            }
        }
#pragma unroll
        for (int i = 0; i < BN / 64; i++) {
            int n = i * 64 + srow;
            const float4* pb = (const float4*)(B + (size_t)n * K + k0 + skq);
            float4 u0 = pb[0], u1 = pb[1];
            f16x8 bv;
            bv[0] = (f16)u0.x; bv[1] = (f16)u0.y; bv[2] = (f16)u0.z; bv[3] = (f16)u0.w;
            bv[4] = (f16)u1.x; bv[5] = (f16)u1.y; bv[6] = (f16)u1.z; bv[7] = (f16)u1.w;
            *(f16x8*)&bs[n][skq] = bv;
        }
        __syncthreads();

        f16x8 af[MF], bf[4];
#pragma unroll
        for (int i = 0; i < MF; i++)
            af[i] = *(const f16x8*)&as[wm * WM + i * 16 + lrow][ksel];
#pragma unroll
        for (int j = 0; j < 4; j++)
            bf[j] = *(const f16x8*)&bs[wn * 64 + j * 16 + lrow][ksel];
#pragma unroll
        for (int i = 0; i < MF; i++)
#pragma unroll
            for (int j = 0; j < 4; j++)
                acc[i][j] = __builtin_amdgcn_mfma_f32_16x16x32_f16(af[i], bf[j], acc[i][j], 0, 0, 0);
        __syncthreads();
    }

    // C store
#pragma unroll
    for (int i = 0; i < MF; i++) {
        int r0 = row0 + wm * WM + i * 16 + (lane >> 4) * 4;
#pragma unroll
        for (int j = 0; j < 4; j++) {
            int col = wn * 64 + j * 16 + (lane & 15);
#pragma unroll
            for (int r = 0; r < 4; r++) {
                int gr = r0 + r;
                if (gr < M) C[(size_t)gr * BN + col] = (f16)acc[i][j][r];
            }
        }
    }

    // fused el/er (head = wn)
#pragma unroll
    for (int i = 0; i < MF; i++) {
        float ea[4] = {}, eb[4] = {};
#pragma unroll
        for (int j = 0; j < 4; j++) {
            int col = wn * 64 + j * 16 + (lane & 15);
            float av = al[col], rv = ar[col];
#pragma unroll
            for (int r = 0; r < 4; r++) {
                ea[r] += acc[i][j][r] * av;
                eb[r] += acc[i][j][r] * rv;
            }
        }
#pragma unroll
        for (int o = 1; o <= 8; o <<= 1) {
#pragma unroll
            for (int r = 0; r < 4; r++) {
                ea[r] += __shfl_xor(ea[r], o);
                eb[r] += __shfl_xor(eb[r], o);
            }
        }
        if ((lane & 15) == 0) {
            int r0 = row0 + wm * WM + i * 16 + (lane >> 4) * 4;
#pragma unroll
            for (int r = 0; r < 4; r++) {
                int gr = r0 + r;
                if (gr < M) {
                    el[gr * WAVES_N + wn] = ea[r];
                    er[gr * WAVES_N + wn] = eb[r];
                }
            }
        }
    }
}

// ---------------- barrier-free 1-wave MFMA segment aggregation ----------------
// Block = 64 threads = ONE WAVE, owns (16 dst nodes) x (one head: blockIdx.y).
// Per 32-edge K-step: C[16n][64f] += A[16n][32e] x H[32e][64f] via 4 tile-MFMAs
// + 1 ones-MFMA (denominator). A[n][e] = w_e = exp(leaky(elg+er)-CSH), masked.
// No __syncthreads: cross-lane LDS visibility within one wave needs only
// s_waitcnt lgkmcnt(0) (one ds_write instr covers all 64 lanes) + a "memory"
// clobber so the compiler can't hoist the dependent LDS reads (rule-18 analog).
// Staging: lane l, iter i: edge e=(l>>3)*4+((l>>1)&3), feat=head*64+16i+8(l&1)
// -> LDS elem i*512 + 8l (linear per instr: 0 conflicts); layout matches
// ds_read_b64_tr_b16 (tile ti at lh[ti*512], lane l -> H[4*(l>>4)+j][l&15]).
// K-perm sigma(kb,j): j<4 -> 4*kb+j ; j>=4 -> 16+4*kb+(j-4); A uses same sigma.
// 1-deep prefetch: issue(k+32) right after this step's LDS writes complete;
// vmcnt waits land at the next step's LDS writes (compiler-managed).

template <int HEADS, bool RELU, typename TOUT>
__global__ __launch_bounds__(64) void agg_mfma(
        const f16* __restrict__ h, const float* __restrict__ elg,
        const float* __restrict__ er, const float* __restrict__ bias,
        const int* __restrict__ indptr, const int* __restrict__ csrc,
        TOUT* __restrict__ out, int N, int E) {
    constexpr int F = HEADS * 64;
    constexpr float CSH = 5.0f;

    __shared__ f16 lh[4 * 512];
    __shared__ unsigned int af_s[32];
    __shared__ float er_s[16];
    __shared__ int iptr_s[17];

    int lane = threadIdx.x;           // 0..63
    int head = blockIdx.y;
    int n0 = blockIdx.x * 16;
    int n_ = lane & 15, kb = lane >> 4;
    int e_ = (lane >> 3) * 4 + ((lane >> 1) & 3);

    if (lane < 17) {
        int nn = n0 + lane;
        iptr_s[lane] = indptr[nn < N ? nn : N];
    }
    if (lane < 16) {
        int nn = n0 + lane;
        er_s[lane] = (nn < N) ? er[nn * HEADS + head] : 0.f;
    }
    asm volatile("s_waitcnt lgkmcnt(0)" ::: "memory");
    int kbeg = iptr_s[0], kend = iptr_s[16];

    f32x4 acc[4];
#pragma unroll
    for (int i = 0; i < 4; i++) acc[i] = (f32x4){0.f, 0.f, 0.f, 0.f};
    f32x4 acc_s = {0.f, 0.f, 0.f, 0.f};

    f16x8 bones;
#pragma unroll
    for (int i = 0; i < 8; i++) bones[i] = (f16)((n_ == 0) ? 1.f : 0.f);

    f16x8 rg[4];
    unsigned int pk = 0;

    auto leaky = [](float v) { return v >= 0.f ? v : NEG_SLOPE * v; };

    // all loads independent; alpha math in registers (overlap region)
    auto issue = [&](int kb0) {
        int pos = kb0 + e_;
        int posc = pos < E ? pos : E - 1;
        const f16* row = h + (size_t)csrc[posc] * F + head * 64 + 8 * (lane & 1);
#pragma unroll
        for (int i = 0; i < 4; i++)
            rg[i] = *(const f16x8*)(row + 16 * i);
        if (lane < 32) {
            int p2 = kb0 + lane;
            int p2c = p2 < E ? p2 : E - 1;
            bool ok = p2 < kend;
            float ev = elg[(size_t)p2c * HEADS + head];
            unsigned int owner = 0;
#pragma unroll
            for (int i = 1; i < 16; i++) owner += (p2 >= iptr_s[i]) ? 1u : 0u;
            float lg = leaky(ev + er_s[owner]);
            f16 w16 = (f16)__expf(lg - CSH);
            pk = ok ? ((owner << 16) | (unsigned int)__builtin_bit_cast(unsigned short, w16)) : 0u;
        }
    };

    auto dostep = [&](int kb0) {
        // WAR-safe: all prior-step LDS reads drained by pre-MFMA lgkmcnt(0)
#pragma unroll
        for (int i = 0; i < 4; i++)
            *(f16x8*)&lh[i * 512 + lane * 8] = rg[i];
        if (lane < 32) af_s[lane] = pk;
        asm volatile("s_waitcnt lgkmcnt(0)" ::: "memory");
        __builtin_amdgcn_sched_barrier(0);
        if (kb0 + 32 < kend) issue(kb0 + 32);   // refill, consumed next step

        // A fragment: w[sigma(kb,jj)] masked by owner==n_
        union { unsigned int u[4]; f16x8 v; } afr;
#pragma unroll
        for (int jj = 0; jj < 8; jj++) {
            int e = (jj < 4) ? (kb * 4 + jj) : (16 + kb * 4 + (jj - 4));
            unsigned int v = af_s[e];
            unsigned int ab = ((v >> 16) == (unsigned int)n_) ? (v & 0xffffu) : 0u;
            if (jj & 1) afr.u[jj >> 1] |= ab << 16;
            else        afr.u[jj >> 1] = ab;
        }

        // B fragments via hardware transpose read (4 tiles = 64 feats)
        f16x4 b0[4], b1[4];
#pragma unroll
        for (int ti = 0; ti < 4; ti++) {
            unsigned int addr = (unsigned int)(size_t)&lh[ti * 512] + lane * 8;
            asm volatile("ds_read_b64_tr_b16 %0, %1" : "=v"(b0[ti]) : "v"(addr));
            asm volatile("ds_read_b64_tr_b16 %0, %1 offset:512" : "=v"(b1[ti]) : "v"(addr));
        }
        asm volatile("s_waitcnt lgkmcnt(0)");
        __builtin_amdgcn_sched_barrier(0);
#pragma unroll
        for (int ti = 0; ti < 4; ti++) {
            f16x8 bfr = __builtin_shufflevector(b0[ti], b1[ti], 0, 1, 2, 3, 4, 5, 6, 7);
            acc[ti] = __builtin_amdgcn_mfma_f32_16x16x32_f16(afr.v, bfr, acc[ti], 0, 0, 0);
        }
        acc_s = __builtin_amdgcn_mfma_f32_16x16x32_f16(afr.v, bones, acc_s, 0, 0, 0);
    };

    if (kbeg < kend) issue(kbeg);
    for (int k = kbeg; k < kend; k += 32) dostep(k);

    // denominator: s for row group kb sits in lane kb*16 (col 0)
    float sv[4];
#pragma unroll
    for (int r = 0; r < 4; r++) sv[r] = __shfl(acc_s[r], lane & 48);

    // epilogue: D row=(lane>>4)*4+r (node), col=lane&15 (feat)
#pragma unroll
    for (int ti = 0; ti < 4; ti++) {
        int col = head * 64 + ti * 16 + n_;
        float bv = bias[col];
#pragma unroll
        for (int r = 0; r < 4; r++) {
            int nn = n0 + kb * 4 + r;
            if (nn < N) {
                float inv = sv[r] > 0.f ? 1.f / sv[r] : 0.f;
                float v = acc[ti][r] * inv + bv;
                if (RELU) v = fmaxf(v, 0.f);
                out[(size_t)nn * F + col] = (TOUT)v;
            }
        }
    }
}

// ---------------- launch ----------------

extern "C" void kernel_launch(void* const* d_in, const int* in_sizes, int n_in,
                              void* d_out, int out_size, void* d_ws, size_t ws_size,
                              hipStream_t stream) {
    const float* x   = (const float*)d_in[0];
    const int*   src = (const int*)d_in[1];
    const int*   dst = (const int*)d_in[2];
    const float* W0  = (const float*)d_in[3];
    const float* al0 = (const float*)d_in[4];
    const float* ar0 = (const float*)d_in[5];
    const float* b0  = (const float*)d_in[6];
    const float* W1  = (const float*)d_in[7];
    const float* al1 = (const float*)d_in[8];
    const float* ar1 = (const float*)d_in[9];
    const float* b1  = (const float*)d_in[10];
    float* out = (float*)d_out;

    const int N = in_sizes[0] / 256;  // 50000
    const int E = in_sizes[1];        // 800000

    char* ws = (char*)d_ws;
    size_t off = 0;
    auto alloc = [&](size_t bytes) -> void* {
        void* p = ws + off;
        off += (bytes + 255) / 256 * 256;
        return p;
    };
    f16* h0        = (f16*)alloc((size_t)N * 256 * 2);
    f16* y         = (f16*)alloc((size_t)N * 256 * 2);
    f16* h1        = (f16*)alloc((size_t)N * 64 * 2);
    float* el0     = (float*)alloc((size_t)N * 4 * 4);
    float* er0     = (float*)alloc((size_t)N * 4 * 4);
    float* el1     = (float*)alloc((size_t)N * 4);
    float* er1     = (float*)alloc((size_t)N * 4);
    float* elg0    = (float*)alloc((size_t)E * 4 * 4);
    float* elg1    = (float*)alloc((size_t)E * 4);
    int* counts    = (int*)alloc((size_t)N * 4);
    int* indptr    = (int*)alloc((size_t)(N + 1) * 4);
    int* cursor    = (int*)alloc((size_t)N * 4);
    int* csrc      = (int*)alloc((size_t)E * 4);
    int* blocksums = (int*)alloc(64 * 4);

    // ---- CSR build (by dst): multi-block scan, no memcpy ----
    hipMemsetAsync(counts, 0, (size_t)N * 4, stream);
    count_dst<<<(E + 255) / 256, 256, 0, stream>>>(dst, counts, E);
    int nb = (N + 1023) / 1024;  // 49
    scan_local<<<nb, 256, 0, stream>>>(counts, indptr, blocksums, N);
    scan_carry<<<1, 64, 0, stream>>>(blocksums, nb);
    scan_add<<<nb, 256, 0, stream>>>(indptr, cursor, blocksums, N, E);
    fill_csr<<<(E + 255) / 256, 256, 0, stream>>>(dst, src, cursor, csrc, E);

    int mtiles = (N + 63) / 64;   // 782
    int atiles = (N + 15) / 16;   // 3125
    int etiles = (E + 255) / 256; // 3125

    // ---- layer 0 ----
    gemm_mfma<256, float><<<mtiles, 256, 0, stream>>>(x, W0, h0, al0, ar0, el0, er0, N);
    elg_kernel<4><<<etiles, 256, 0, stream>>>(el0, csrc, elg0, E);
    agg_mfma<4, true, f16><<<dim3(atiles, 4), 64, 0, stream>>>(h0, elg0, er0, b0, indptr, csrc, y, N, E);

    // ---- layer 1 ----
    gemm_mfma<64, f16><<<mtiles, 256, 0, stream>>>(y, W1, h1, al1, ar1, el1, er1, N);
    elg_kernel<1><<<etiles, 256, 0, stream>>>(el1, csrc, elg1, E);
    agg_mfma<1, false, float><<<dim3(atiles, 1), 64, 0, stream>>>(h1, elg1, er1, b1, indptr, csrc, out, N, E);
}

// Round 14
// 246.267 us; speedup vs baseline: 1.5225x; 1.0327x over previous
//
#include <hip/hip_runtime.h>
#include <math.h>

#define NEG_SLOPE 0.2f

using f16   = _Float16;
using f16x4 = __attribute__((ext_vector_type(4))) _Float16;
using f16x8 = __attribute__((ext_vector_type(8))) _Float16;
using f32x4 = __attribute__((ext_vector_type(4))) float;

// ---------------- CSR build ----------------

__global__ void count_dst(const int* __restrict__ dst, int* __restrict__ counts, int E) {
    int e = blockIdx.x * blockDim.x + threadIdx.x;
    if (e < E) atomicAdd(&counts[dst[e]], 1);
}

__global__ void scan_local(const int* __restrict__ counts, int* __restrict__ indptr,
                           int* __restrict__ blocksums, int n) {
    __shared__ int sdata[256];
    int b = blockIdx.x, t = threadIdx.x;
    int base = b * 1024 + t * 4;
    int v[4];
    int sum = 0;
#pragma unroll
    for (int j = 0; j < 4; j++) {
        int idx = base + j;
        v[j] = (idx < n) ? counts[idx] : 0;
        sum += v[j];
    }
    sdata[t] = sum;
    __syncthreads();
    for (int o = 1; o < 256; o <<= 1) {
        int u = 0;
        if (t >= o) u = sdata[t - o];
        __syncthreads();
        if (t >= o) sdata[t] += u;
        __syncthreads();
    }
    int excl = (t > 0) ? sdata[t - 1] : 0;
    int run = excl;
#pragma unroll
    for (int j = 0; j < 4; j++) {
        int idx = base + j;
        if (idx < n) indptr[idx] = run;
        run += v[j];
    }
    if (t == 255) blocksums[b] = sdata[255];
}

__global__ void scan_carry(int* __restrict__ blocksums, int nb) {
    int t = threadIdx.x;
    int v = (t < nb) ? blocksums[t] : 0;
    int orig = v;
#pragma unroll
    for (int o = 1; o < 64; o <<= 1) {
        int u = __shfl_up(v, o);
        if (t >= o) v += u;
    }
    if (t < nb) blocksums[t] = v - orig;
}

// adds carry; also writes cursor (replaces the d2d memcpy)
__global__ void scan_add(int* __restrict__ indptr, int* __restrict__ cursor,
                         const int* __restrict__ blocksums, int n, int Etot) {
    int b = blockIdx.x, t = threadIdx.x;
    int base = b * 1024 + t * 4;
    int add = blocksums[b];
#pragma unroll
    for (int j = 0; j < 4; j++) {
        int idx = base + j;
        if (idx < n) {
            int v = indptr[idx] + add;
            indptr[idx] = v;
            cursor[idx] = v;
        }
    }
    if (b == 0 && t == 0) indptr[n] = Etot;
}

__global__ void fill_csr(const int* __restrict__ dst, const int* __restrict__ src,
                         int* __restrict__ cursor, int* __restrict__ csrc, int E) {
    int e = blockIdx.x * blockDim.x + threadIdx.x;
    if (e < E) {
        int p = atomicAdd(&cursor[dst[e]], 1);
        csrc[p] = src[e];
    }
}

// ---------------- edge el gather: elg[pos][h] = el[csrc[pos]][h] ----------------

template <int HEADS>
__global__ __launch_bounds__(256) void elg_kernel(const float* __restrict__ el,
                                                  const int* __restrict__ csrc,
                                                  float* __restrict__ elg, int E) {
    int i = blockIdx.x * blockDim.x + threadIdx.x;
    if (i < E) {
        int sd = csrc[i];
        if constexpr (HEADS == 4)
            *(float4*)&elg[(size_t)i * 4] = *(const float4*)&el[(size_t)sd * 4];
        else
            elg[i] = el[sd];
    }
}

// ---------------- f16-MFMA GEMM + fused el/er ----------------

template <int BN, typename TA>
__global__ __launch_bounds__(256) void gemm_mfma(const TA* __restrict__ A,
                                                 const float* __restrict__ B,
                                                 f16* __restrict__ C,
                                                 const float* __restrict__ al,
                                                 const float* __restrict__ ar,
                                                 float* __restrict__ el,
                                                 float* __restrict__ er, int M) {
    constexpr int K = 256;
    constexpr int WAVES_N = BN / 64;
    constexpr int WAVES_M = 4 / WAVES_N;
    constexpr int WM = 64 / WAVES_M;
    constexpr int MF = WM / 16;

    __shared__ f16 as[64][40];
    __shared__ f16 bs[BN][40];

    int t = threadIdx.x;
    int wave = t >> 6, lane = t & 63;
    int wn = wave / WAVES_M;
    int wm = wave % WAVES_M;
    int row0 = blockIdx.x * 64;

    int srow = t >> 2;
    int skq = (t & 3) * 8;

    int lrow = lane & 15;
    int ksel = (lane >> 4) * 8;

    f32x4 acc[MF][4] = {};

    for (int k0 = 0; k0 < K; k0 += 32) {
        {
            int gr = row0 + srow;
            gr = gr < M ? gr : M - 1;
            if constexpr (sizeof(TA) == 4) {
                const float4* pa = (const float4*)(A + (size_t)gr * K + k0 + skq);
                float4 u0 = pa[0], u1 = pa[1];
                f16x8 av;
                av[0] = (f16)u0.x; av[1] = (f16)u0.y; av[2] = (f16)u0.z; av[3] = (f16)u0.w;
                av[4] = (f16)u1.x; av[5] = (f16)u1.y; av[6] = (f16)u1.z; av[7] = (f16)u1.w;
                *(f16x8*)&as[srow][skq] = av;
            } else {
                *(f16x8*)&as[srow][skq] = *(const f16x8*)(A + (size_t)gr * K + k0 + skq);
            }
        }
#pragma unroll
        for (int i = 0; i < BN / 64; i++) {
            int n = i * 64 + srow;
            const float4* pb = (const float4*)(B + (size_t)n * K + k0 + skq);
            float4 u0 = pb[0], u1 = pb[1];
            f16x8 bv;
            bv[0] = (f16)u0.x; bv[1] = (f16)u0.y; bv[2] = (f16)u0.z; bv[3] = (f16)u0.w;
            bv[4] = (f16)u1.x; bv[5] = (f16)u1.y; bv[6] = (f16)u1.z; bv[7] = (f16)u1.w;
            *(f16x8*)&bs[n][skq] = bv;
        }
        __syncthreads();

        f16x8 af[MF], bf[4];
#pragma unroll
        for (int i = 0; i < MF; i++)
            af[i] = *(const f16x8*)&as[wm * WM + i * 16 + lrow][ksel];
#pragma unroll
        for (int j = 0; j < 4; j++)
            bf[j] = *(const f16x8*)&bs[wn * 64 + j * 16 + lrow][ksel];
#pragma unroll
        for (int i = 0; i < MF; i++)
#pragma unroll
            for (int j = 0; j < 4; j++)
                acc[i][j] = __builtin_amdgcn_mfma_f32_16x16x32_f16(af[i], bf[j], acc[i][j], 0, 0, 0);
        __syncthreads();
    }

    // C store
#pragma unroll
    for (int i = 0; i < MF; i++) {
        int r0 = row0 + wm * WM + i * 16 + (lane >> 4) * 4;
#pragma unroll
        for (int j = 0; j < 4; j++) {
            int col = wn * 64 + j * 16 + (lane & 15);
#pragma unroll
            for (int r = 0; r < 4; r++) {
                int gr = r0 + r;
                if (gr < M) C[(size_t)gr * BN + col] = (f16)acc[i][j][r];
            }
        }
    }

    // fused el/er (head = wn)
#pragma unroll
    for (int i = 0; i < MF; i++) {
        float ea[4] = {}, eb[4] = {};
#pragma unroll
        for (int j = 0; j < 4; j++) {
            int col = wn * 64 + j * 16 + (lane & 15);
            float av = al[col], rv = ar[col];
#pragma unroll
            for (int r = 0; r < 4; r++) {
                ea[r] += acc[i][j][r] * av;
                eb[r] += acc[i][j][r] * rv;
            }
        }
#pragma unroll
        for (int o = 1; o <= 8; o <<= 1) {
#pragma unroll
            for (int r = 0; r < 4; r++) {
                ea[r] += __shfl_xor(ea[r], o);
                eb[r] += __shfl_xor(eb[r], o);
            }
        }
        if ((lane & 15) == 0) {
            int r0 = row0 + wm * WM + i * 16 + (lane >> 4) * 4;
#pragma unroll
            for (int r = 0; r < 4; r++) {
                int gr = r0 + r;
                if (gr < M) {
                    el[gr * WAVES_N + wn] = ea[r];
                    er[gr * WAVES_N + wn] = eb[r];
                }
            }
        }
    }
}

// ---------------- barrier-free multi-wave MFMA segment aggregation ----------------
// Block = 256 threads = 4 INDEPENDENT waves (packaging only -- no __syncthreads;
// dodges the 16-workgroups/CU cap that held 1-wave blocks at 44% occupancy, R13).
// Wave wv owns unit = blockIdx.x*4+wv = (node-tile, head): 16 dst nodes x 64 feats.
// Per 32-edge K-step: C[16n][64f] += A[16n][32e] x H[32e][64f] via 4 tile-MFMAs
// + 1 ones-MFMA (denominator). A[n][e] = w_e = exp(leaky(elg+er)-CSH), masked.
// Within-wave LDS visibility: s_waitcnt lgkmcnt(0) + "memory" clobber only.
// Staging: lane l, iter i: edge e=(l>>3)*4+((l>>1)&3), feat=head*64+16i+8(l&1)
// -> per-wave LDS elem i*512 + 8l (linear per instr: 0 conflicts); layout
// matches ds_read_b64_tr_b16 (tile ti at lh[wv][ti*512], lane l -> H[4*(l>>4)+j][l&15]).
// K-perm sigma(kb,j): j<4 -> 4*kb+j ; j>=4 -> 16+4*kb+(j-4); A uses same sigma.
// 1-deep prefetch (R9/R11-proven: TLP is the latency hider, keep VGPR at 44).

template <int HEADS, bool RELU, typename TOUT>
__global__ __launch_bounds__(256) void agg_mfma(
        const f16* __restrict__ h, const float* __restrict__ elg,
        const float* __restrict__ er, const float* __restrict__ bias,
        const int* __restrict__ indptr, const int* __restrict__ csrc,
        TOUT* __restrict__ out, int N, int E) {
    constexpr int F = HEADS * 64;
    constexpr float CSH = 5.0f;

    __shared__ f16 lh[4][4 * 512];
    __shared__ unsigned int af_s[4][32];
    __shared__ float er_s[4][16];
    __shared__ int iptr_s[4][17];

    int t = threadIdx.x;
    int wv = t >> 6, lane = t & 63;
    int unit = blockIdx.x * 4 + wv;
    int tile = (HEADS == 4) ? (unit >> 2) : unit;
    int head = (HEADS == 4) ? (unit & 3) : 0;
    int n0 = tile * 16;
    if (n0 >= N) return;   // safe: no cross-wave sync anywhere

    int n_ = lane & 15, kb = lane >> 4;
    int e_ = (lane >> 3) * 4 + ((lane >> 1) & 3);

    if (lane < 17) {
        int nn = n0 + lane;
        iptr_s[wv][lane] = indptr[nn < N ? nn : N];
    }
    if (lane < 16) {
        int nn = n0 + lane;
        er_s[wv][lane] = (nn < N) ? er[nn * HEADS + head] : 0.f;
    }
    asm volatile("s_waitcnt lgkmcnt(0)" ::: "memory");
    int kbeg = iptr_s[wv][0], kend = iptr_s[wv][16];

    f32x4 acc[4];
#pragma unroll
    for (int i = 0; i < 4; i++) acc[i] = (f32x4){0.f, 0.f, 0.f, 0.f};
    f32x4 acc_s = {0.f, 0.f, 0.f, 0.f};

    f16x8 bones;
#pragma unroll
    for (int i = 0; i < 8; i++) bones[i] = (f16)((n_ == 0) ? 1.f : 0.f);

    f16x8 rg[4];
    unsigned int pk = 0;

    auto leaky = [](float v) { return v >= 0.f ? v : NEG_SLOPE * v; };

    // all loads independent; alpha math in registers (overlap region)
    auto issue = [&](int kb0) {
        int pos = kb0 + e_;
        int posc = pos < E ? pos : E - 1;
        const f16* row = h + (size_t)csrc[posc] * F + head * 64 + 8 * (lane & 1);
#pragma unroll
        for (int i = 0; i < 4; i++)
            rg[i] = *(const f16x8*)(row + 16 * i);
        if (lane < 32) {
            int p2 = kb0 + lane;
            int p2c = p2 < E ? p2 : E - 1;
            bool ok = p2 < kend;
            float ev = elg[(size_t)p2c * HEADS + head];
            unsigned int owner = 0;
#pragma unroll
            for (int i = 1; i < 16; i++) owner += (p2 >= iptr_s[wv][i]) ? 1u : 0u;
            float lg = leaky(ev + er_s[wv][owner]);
            f16 w16 = (f16)__expf(lg - CSH);
            pk = ok ? ((owner << 16) | (unsigned int)__builtin_bit_cast(unsigned short, w16)) : 0u;
        }
    };

    auto dostep = [&](int kb0) {
        // WAR-safe: all prior-step LDS reads drained by pre-MFMA lgkmcnt(0)
#pragma unroll
        for (int i = 0; i < 4; i++)
            *(f16x8*)&lh[wv][i * 512 + lane * 8] = rg[i];
        if (lane < 32) af_s[wv][lane] = pk;
        asm volatile("s_waitcnt lgkmcnt(0)" ::: "memory");
        __builtin_amdgcn_sched_barrier(0);
        if (kb0 + 32 < kend) issue(kb0 + 32);   // refill, consumed next step

        // A fragment: w[sigma(kb,jj)] masked by owner==n_
        union { unsigned int u[4]; f16x8 v; } afr;
#pragma unroll
        for (int jj = 0; jj < 8; jj++) {
            int e = (jj < 4) ? (kb * 4 + jj) : (16 + kb * 4 + (jj - 4));
            unsigned int v = af_s[wv][e];
            unsigned int ab = ((v >> 16) == (unsigned int)n_) ? (v & 0xffffu) : 0u;
            if (jj & 1) afr.u[jj >> 1] |= ab << 16;
            else        afr.u[jj >> 1] = ab;
        }

        // B fragments via hardware transpose read (4 tiles = 64 feats)
        f16x4 b0[4], b1[4];
#pragma unroll
        for (int ti = 0; ti < 4; ti++) {
            unsigned int addr = (unsigned int)(size_t)&lh[wv][ti * 512] + lane * 8;
            asm volatile("ds_read_b64_tr_b16 %0, %1" : "=v"(b0[ti]) : "v"(addr));
            asm volatile("ds_read_b64_tr_b16 %0, %1 offset:512" : "=v"(b1[ti]) : "v"(addr));
        }
        asm volatile("s_waitcnt lgkmcnt(0)");
        __builtin_amdgcn_sched_barrier(0);
#pragma unroll
        for (int ti = 0; ti < 4; ti++) {
            f16x8 bfr = __builtin_shufflevector(b0[ti], b1[ti], 0, 1, 2, 3, 4, 5, 6, 7);
            acc[ti] = __builtin_amdgcn_mfma_f32_16x16x32_f16(afr.v, bfr, acc[ti], 0, 0, 0);
        }
        acc_s = __builtin_amdgcn_mfma_f32_16x16x32_f16(afr.v, bones, acc_s, 0, 0, 0);
    };

    if (kbeg < kend) issue(kbeg);
    for (int k = kbeg; k < kend; k += 32) dostep(k);

    // denominator: s for row group kb sits in lane kb*16 (col 0)
    float sv[4];
#pragma unroll
    for (int r = 0; r < 4; r++) sv[r] = __shfl(acc_s[r], lane & 48);

    // epilogue: D row=(lane>>4)*4+r (node), col=lane&15 (feat)
#pragma unroll
    for (int ti = 0; ti < 4; ti++) {
        int col = head * 64 + ti * 16 + n_;
        float bv = bias[col];
#pragma unroll
        for (int r = 0; r < 4; r++) {
            int nn = n0 + kb * 4 + r;
            if (nn < N) {
                float inv = sv[r] > 0.f ? 1.f / sv[r] : 0.f;
                float v = acc[ti][r] * inv + bv;
                if (RELU) v = fmaxf(v, 0.f);
                out[(size_t)nn * F + col] = (TOUT)v;
            }
        }
    }
}

// ---------------- launch ----------------

extern "C" void kernel_launch(void* const* d_in, const int* in_sizes, int n_in,
                              void* d_out, int out_size, void* d_ws, size_t ws_size,
                              hipStream_t stream) {
    const float* x   = (const float*)d_in[0];
    const int*   src = (const int*)d_in[1];
    const int*   dst = (const int*)d_in[2];
    const float* W0  = (const float*)d_in[3];
    const float* al0 = (const float*)d_in[4];
    const float* ar0 = (const float*)d_in[5];
    const float* b0  = (const float*)d_in[6];
    const float* W1  = (const float*)d_in[7];
    const float* al1 = (const float*)d_in[8];
    const float* ar1 = (const float*)d_in[9];
    const float* b1  = (const float*)d_in[10];
    float* out = (float*)d_out;

    const int N = in_sizes[0] / 256;  // 50000
    const int E = in_sizes[1];        // 800000

    char* ws = (char*)d_ws;
    size_t off = 0;
    auto alloc = [&](size_t bytes) -> void* {
        void* p = ws + off;
        off += (bytes + 255) / 256 * 256;
        return p;
    };
    f16* h0        = (f16*)alloc((size_t)N * 256 * 2);
    f16* y         = (f16*)alloc((size_t)N * 256 * 2);
    f16* h1        = (f16*)alloc((size_t)N * 64 * 2);
    float* el0     = (float*)alloc((size_t)N * 4 * 4);
    float* er0     = (float*)alloc((size_t)N * 4 * 4);
    float* el1     = (float*)alloc((size_t)N * 4);
    float* er1     = (float*)alloc((size_t)N * 4);
    float* elg0    = (float*)alloc((size_t)E * 4 * 4);
    float* elg1    = (float*)alloc((size_t)E * 4);
    int* counts    = (int*)alloc((size_t)N * 4);
    int* indptr    = (int*)alloc((size_t)(N + 1) * 4);
    int* cursor    = (int*)alloc((size_t)N * 4);
    int* csrc      = (int*)alloc((size_t)E * 4);
    int* blocksums = (int*)alloc(64 * 4);

    // ---- CSR build (by dst): multi-block scan, no memcpy ----
    hipMemsetAsync(counts, 0, (size_t)N * 4, stream);
    count_dst<<<(E + 255) / 256, 256, 0, stream>>>(dst, counts, E);
    int nb = (N + 1023) / 1024;  // 49
    scan_local<<<nb, 256, 0, stream>>>(counts, indptr, blocksums, N);
    scan_carry<<<1, 64, 0, stream>>>(blocksums, nb);
    scan_add<<<nb, 256, 0, stream>>>(indptr, cursor, blocksums, N, E);
    fill_csr<<<(E + 255) / 256, 256, 0, stream>>>(dst, src, cursor, csrc, E);

    int mtiles = (N + 63) / 64;   // 782
    int atiles = (N + 15) / 16;   // 3125
    int etiles = (E + 255) / 256; // 3125

    // ---- layer 0 ----
    gemm_mfma<256, float><<<mtiles, 256, 0, stream>>>(x, W0, h0, al0, ar0, el0, er0, N);
    elg_kernel<4><<<etiles, 256, 0, stream>>>(el0, csrc, elg0, E);
    // units = atiles*4 (tile,head); 4 independent waves per block
    agg_mfma<4, true, f16><<<atiles, 256, 0, stream>>>(h0, elg0, er0, b0, indptr, csrc, y, N, E);

    // ---- layer 1 ----
    gemm_mfma<64, f16><<<mtiles, 256, 0, stream>>>(y, W1, h1, al1, ar1, el1, er1, N);
    elg_kernel<1><<<etiles, 256, 0, stream>>>(el1, csrc, elg1, E);
    agg_mfma<1, false, float><<<(atiles + 3) / 4, 256, 0, stream>>>(h1, elg1, er1, b1, indptr, csrc, out, N, E);
}